// Round 1
// 260.935 us; speedup vs baseline: 1.1506x; 1.1506x over previous
//
#include <hip/hip_runtime.h>
#include <hip/hip_bf16.h>

#define NNODES 100000
#define DIN 128
#define DH 64
#define BSH 9
#define BNODES 512                             // 1 << BSH
#define NBUCK ((NNODES + BNODES - 1) >> BSH)   // 196
#define SRCMASK 0x1FFFF                        // N < 2^17

typedef short s16x8 __attribute__((ext_vector_type(8)));
typedef float f32x4 __attribute__((ext_vector_type(4)));

static __device__ __forceinline__ short f2bf(float f) {
  __hip_bfloat16 h = __float2bfloat16(f);   // RTNE
  return *reinterpret_cast<short*>(&h);
}
static __device__ __forceinline__ float bf2f(short s) {
  return __uint_as_float(((unsigned)(unsigned short)s) << 16);
}

// ---------------- dense transforms via MFMA (hi/lo bf16 split ~ 17-bit mantissa) ----------------
// mfma_f32_16x16x32_bf16 layouts (m89-verified):
//   A: row = lane&15, k = (lane>>4)*8 + i
//   B: col = lane&15, k = (lane>>4)*8 + i
//   D: col = lane&15, row = (lane>>4)*4 + reg
// Each wave: 32 output rows (2 row-tiles of 16) x 64 cols (4 col-tiles of 16).
// Block = 4 waves = 128 rows. W staged once per block into LDS in fragment order.

__global__ __launch_bounds__(256, 4) void gemm1_mfma(
    const float* __restrict__ emb, const float* __restrict__ W1,
    __hip_bfloat16* __restrict__ x1, int N) {
  __shared__ short Bhi[4 * 4 * 64 * 8];   // [kc][ct][lane][8] = 8192 bf16 = 16 KB
  __shared__ short Blo[4 * 4 * 64 * 8];   // 16 KB
  int tid = threadIdx.x;

  for (int idx = tid; idx < 8192; idx += 256) {
    int i = idx & 7, ln = (idx >> 3) & 63, ct = (idx >> 9) & 3, kc = idx >> 11;
    int k = kc * 32 + (ln >> 4) * 8 + i;
    int col = ct * 16 + (ln & 15);
    float w = W1[k * DH + col];
    short h = f2bf(w);
    Bhi[idx] = h;
    Blo[idx] = f2bf(w - bf2f(h));
  }
  __syncthreads();

  int lane = tid & 63, wv = tid >> 6;
  int r0 = (blockIdx.x * 8 + wv * 2) * 16;   // this wave: rows r0 .. r0+31
  if (r0 >= N) return;

  const int rA = lane & 15, g = lane >> 4;
  f32x4 acc[2][4] = {};

#pragma unroll
  for (int kc = 0; kc < 4; ++kc) {
    s16x8 ahi[2], alo[2];
#pragma unroll
    for (int rt = 0; rt < 2; ++rt) {
      int r = r0 + rt * 16 + rA;
      float av[8];
      if (r < N) {
        const float4* ap = (const float4*)(emb + (long)r * DIN + kc * 32 + g * 8);
        float4 v0 = ap[0], v1 = ap[1];
        av[0] = v0.x; av[1] = v0.y; av[2] = v0.z; av[3] = v0.w;
        av[4] = v1.x; av[5] = v1.y; av[6] = v1.z; av[7] = v1.w;
      } else {
#pragma unroll
        for (int i = 0; i < 8; ++i) av[i] = 0.f;
      }
#pragma unroll
      for (int i = 0; i < 8; ++i) {
        short h = f2bf(av[i]);
        ahi[rt][i] = h;
        alo[rt][i] = f2bf(av[i] - bf2f(h));
      }
    }
#pragma unroll
    for (int ct = 0; ct < 4; ++ct) {
      int fo = ((kc * 4 + ct) * 64 + lane) * 8;
      s16x8 bh = *(const s16x8*)&Bhi[fo];
      s16x8 bl = *(const s16x8*)&Blo[fo];
#pragma unroll
      for (int rt = 0; rt < 2; ++rt) {
        acc[rt][ct] = __builtin_amdgcn_mfma_f32_16x16x32_bf16(ahi[rt], bh, acc[rt][ct], 0, 0, 0);
        acc[rt][ct] = __builtin_amdgcn_mfma_f32_16x16x32_bf16(alo[rt], bh, acc[rt][ct], 0, 0, 0);
        acc[rt][ct] = __builtin_amdgcn_mfma_f32_16x16x32_bf16(ahi[rt], bl, acc[rt][ct], 0, 0, 0);
      }
    }
  }

#pragma unroll
  for (int rt = 0; rt < 2; ++rt) {
#pragma unroll
    for (int j = 0; j < 4; ++j) {
      int row = r0 + rt * 16 + g * 4 + j;
      if (row < N) {
#pragma unroll
        for (int ct = 0; ct < 4; ++ct)
          x1[(long)row * DH + ct * 16 + rA] = __float2bfloat16(acc[rt][ct][j]);
      }
    }
  }
}

__global__ __launch_bounds__(256, 4) void gemm2_mfma(
    const float* __restrict__ agg, const float* __restrict__ W2,
    const float* __restrict__ b1, __hip_bfloat16* __restrict__ x2, int N) {
  __shared__ short Bhi[2 * 4 * 64 * 8];   // 4096 bf16 = 8 KB
  __shared__ short Blo[2 * 4 * 64 * 8];   // 8 KB
  int tid = threadIdx.x;

  for (int idx = tid; idx < 4096; idx += 256) {
    int i = idx & 7, ln = (idx >> 3) & 63, ct = (idx >> 9) & 3, kc = (idx >> 11) & 1;
    int k = kc * 32 + (ln >> 4) * 8 + i;
    int col = ct * 16 + (ln & 15);
    float w = W2[k * DH + col];
    short h = f2bf(w);
    Bhi[idx] = h;
    Blo[idx] = f2bf(w - bf2f(h));
  }
  __syncthreads();

  int lane = tid & 63, wv = tid >> 6;
  int r0 = (blockIdx.x * 8 + wv * 2) * 16;
  if (r0 >= N) return;

  const int rA = lane & 15, g = lane >> 4;
  f32x4 acc[2][4] = {};

#pragma unroll
  for (int kc = 0; kc < 2; ++kc) {
    const float4* bp = (const float4*)(b1 + kc * 32 + g * 8);
    float4 b0 = bp[0], b4 = bp[1];
    float bv[8] = {b0.x, b0.y, b0.z, b0.w, b4.x, b4.y, b4.z, b4.w};
    s16x8 ahi[2], alo[2];
#pragma unroll
    for (int rt = 0; rt < 2; ++rt) {
      int r = r0 + rt * 16 + rA;
      float av[8];
      if (r < N) {
        const float4* ap = (const float4*)(agg + (long)r * DH + kc * 32 + g * 8);
        float4 v0 = ap[0], v1 = ap[1];
        av[0] = v0.x; av[1] = v0.y; av[2] = v0.z; av[3] = v0.w;
        av[4] = v1.x; av[5] = v1.y; av[6] = v1.z; av[7] = v1.w;
      } else {
#pragma unroll
        for (int i = 0; i < 8; ++i) av[i] = -1e30f;  // relu() -> 0 anyway
      }
#pragma unroll
      for (int i = 0; i < 8; ++i) {
        float a = fmaxf(av[i] + bv[i], 0.f);
        short h = f2bf(a);
        ahi[rt][i] = h;
        alo[rt][i] = f2bf(a - bf2f(h));
      }
    }
#pragma unroll
    for (int ct = 0; ct < 4; ++ct) {
      int fo = ((kc * 4 + ct) * 64 + lane) * 8;
      s16x8 bh = *(const s16x8*)&Bhi[fo];
      s16x8 bl = *(const s16x8*)&Blo[fo];
#pragma unroll
      for (int rt = 0; rt < 2; ++rt) {
        acc[rt][ct] = __builtin_amdgcn_mfma_f32_16x16x32_bf16(ahi[rt], bh, acc[rt][ct], 0, 0, 0);
        acc[rt][ct] = __builtin_amdgcn_mfma_f32_16x16x32_bf16(alo[rt], bh, acc[rt][ct], 0, 0, 0);
        acc[rt][ct] = __builtin_amdgcn_mfma_f32_16x16x32_bf16(ahi[rt], bl, acc[rt][ct], 0, 0, 0);
      }
    }
  }

#pragma unroll
  for (int rt = 0; rt < 2; ++rt) {
#pragma unroll
    for (int j = 0; j < 4; ++j) {
      int row = r0 + rt * 16 + g * 4 + j;
      if (row < N) {
#pragma unroll
        for (int ct = 0; ct < 4; ++ct)
          x2[(long)row * DH + ct * 16 + rA] = __float2bfloat16(acc[rt][ct][j]);
      }
    }
  }
}

// ---------------- bucketed CSR build ----------------

__global__ __launch_bounds__(256) void bucket_hist(
    const int* __restrict__ dsts, int* __restrict__ bcnt, int E) {
  __shared__ int c[NBUCK];
  for (int i = threadIdx.x; i < NBUCK; i += 256) c[i] = 0;
  __syncthreads();
  int e0 = blockIdx.x * 4096;
  int e1 = min(E, e0 + 4096);
  for (int e = e0 + threadIdx.x; e < e1; e += 256)
    atomicAdd(&c[dsts[e] >> BSH], 1);
  __syncthreads();
  for (int i = threadIdx.x; i < NBUCK; i += 256)
    if (c[i]) atomicAdd(&bcnt[i], c[i]);
}

__global__ __launch_bounds__(256) void bucket_scan(
    const int* __restrict__ bcnt, int* __restrict__ bOffs,
    int* __restrict__ bCur, int* __restrict__ offs, int N) {
  int t = threadIdx.x;
  __shared__ int s[256];
  int v = (t < NBUCK) ? bcnt[t] : 0;
  s[t] = v;
  __syncthreads();
  for (int d = 1; d < 256; d <<= 1) {
    int u = (t >= d) ? s[t - d] : 0;
    __syncthreads();
    s[t] += u;
    __syncthreads();
  }
  if (t < NBUCK) { bOffs[t] = s[t] - v; bCur[t] = s[t] - v; }
  if (t == NBUCK - 1) { bOffs[NBUCK] = s[t]; offs[N] = s[t]; }
}

__global__ __launch_bounds__(512) void bucket_fill(
    const int* __restrict__ srcs, const int* __restrict__ dsts,
    const float* __restrict__ w, int* __restrict__ bCur,
    int2* __restrict__ esw, int E) {
  __shared__ int cnt[NBUCK];
  __shared__ int base[NBUCK];
  int tid = threadIdx.x;
  for (int i = tid; i < NBUCK; i += 512) cnt[i] = 0;
  __syncthreads();
  int e0 = blockIdx.x * 8192;
  int pk[16]; int bs[16]; float ww[16];
#pragma unroll
  for (int i = 0; i < 16; ++i) {
    int e = e0 + tid + i * 512;
    if (e < E) {
      int s = srcs[e], d = dsts[e];
      pk[i] = s | ((d & (BNODES - 1)) << 17);
      bs[i] = d >> BSH;
      ww[i] = w[e];
    } else { bs[i] = -1; pk[i] = 0; ww[i] = 0.f; }
  }
#pragma unroll
  for (int i = 0; i < 16; ++i)
    if (bs[i] >= 0) atomicAdd(&cnt[bs[i]], 1);
  __syncthreads();
  for (int b = tid; b < NBUCK; b += 512)
    base[b] = cnt[b] ? atomicAdd(&bCur[b], cnt[b]) : 0;
  __syncthreads();
  for (int i = tid; i < NBUCK; i += 512) cnt[i] = 0;
  __syncthreads();
#pragma unroll
  for (int i = 0; i < 16; ++i) {
    if (bs[i] >= 0) {
      int p = base[bs[i]] + atomicAdd(&cnt[bs[i]], 1);
      esw[p] = make_int2(pk[i], __float_as_int(ww[i]));
    }
  }
}

// one block per bucket: local hist+scan+scatter; writes PACKED 4B pairs:
// src(17 bits) | round(w*2^15)(15 bits) << 17   (w in [0,1))
__global__ __launch_bounds__(512) void csr_build(
    const int2* __restrict__ esw, const int* __restrict__ bOffs,
    int* __restrict__ offs, int* __restrict__ pairs, int N) {
  int b = blockIdx.x;
  int nb0 = b << BSH;
  int st = bOffs[b], en = bOffs[b + 1];
  __shared__ int deg[BNODES];
  __shared__ int cur[BNODES];
  int tid = threadIdx.x;
  deg[tid] = 0;
  __syncthreads();
  for (int k = st + tid; k < en; k += 512)
    atomicAdd(&deg[(esw[k].x >> 17) & (BNODES - 1)], 1);
  __syncthreads();
  int v = deg[tid];
  cur[tid] = v;
  __syncthreads();
  for (int d = 1; d < 512; d <<= 1) {
    int u = (tid >= d) ? cur[tid - d] : 0;
    __syncthreads();
    cur[tid] += u;
    __syncthreads();
  }
  int c = st + cur[tid] - v;
  cur[tid] = c;
  int n = nb0 + tid;
  if (n < N) offs[n] = c;
  __syncthreads();
  for (int k = st + tid; k < en; k += 512) {
    int2 e = esw[k];
    int p = atomicAdd(&cur[(e.x >> 17) & (BNODES - 1)], 1);
    float wv = __int_as_float(e.y);
    int wq = (int)(wv * 32768.f + 0.5f);
    if (wq > 32767) wq = 32767;
    pairs[p] = (e.x & SRCMASK) | (wq << 17);
  }
}

// ---------------- CSR aggregation: 4 features/lane, 4 edges/instr ----------------
// lane = h*16 + fj : h = edge-of-quad (0..3), fj = feature-quad (0..15).
// Gather uint2 (4×bf16): 16 lanes × 8B = one 128B row; one instr = 4 edges.
__global__ __launch_bounds__(256) void agg_quad(
    const int* __restrict__ pairs, const int* __restrict__ offs,
    const uint2* __restrict__ x,   // 4×bf16 per element, 16 per node
    const float* __restrict__ bias, float* __restrict__ out, int N) {
  int wid = (int)(((long)blockIdx.x * 256 + threadIdx.x) >> 6);
  int lane = threadIdx.x & 63;
  if (wid >= N) return;
  int h = lane >> 4;        // edge within quad
  int fj = lane & 15;       // feature-quad index
  int st = offs[wid], en = offs[wid + 1];
  float a0 = 0.f, a1 = 0.f, a2 = 0.f, a3 = 0.f;

  int k = st;
  for (; k + 7 < en; k += 8) {
    unsigned pA = (unsigned)pairs[k + h];
    unsigned pB = (unsigned)pairs[k + 4 + h];
    uint2 xa = x[(pA & SRCMASK) * 16 + fj];
    uint2 xb = x[(pB & SRCMASK) * 16 + fj];
    float wa = (float)(pA >> 17) * (1.f / 32768.f);
    float wb = (float)(pB >> 17) * (1.f / 32768.f);
    a0 += wa * __uint_as_float(xa.x << 16);
    a1 += wa * __uint_as_float(xa.x & 0xFFFF0000u);
    a2 += wa * __uint_as_float(xa.y << 16);
    a3 += wa * __uint_as_float(xa.y & 0xFFFF0000u);
    a0 += wb * __uint_as_float(xb.x << 16);
    a1 += wb * __uint_as_float(xb.x & 0xFFFF0000u);
    a2 += wb * __uint_as_float(xb.y << 16);
    a3 += wb * __uint_as_float(xb.y & 0xFFFF0000u);
  }
  for (; k < en; k += 4) {
    int idx = k + h;
    unsigned p = (idx < en) ? (unsigned)pairs[idx] : 0u;   // w=0 for pad
    uint2 xv = x[(p & SRCMASK) * 16 + fj];
    float wv = (float)(p >> 17) * (1.f / 32768.f);
    a0 += wv * __uint_as_float(xv.x << 16);
    a1 += wv * __uint_as_float(xv.x & 0xFFFF0000u);
    a2 += wv * __uint_as_float(xv.y << 16);
    a3 += wv * __uint_as_float(xv.y & 0xFFFF0000u);
  }
  // sum over the 4 edge-groups (h); lanes with equal fj hold same features
  a0 += __shfl_xor(a0, 16); a0 += __shfl_xor(a0, 32);
  a1 += __shfl_xor(a1, 16); a1 += __shfl_xor(a1, 32);
  a2 += __shfl_xor(a2, 16); a2 += __shfl_xor(a2, 32);
  a3 += __shfl_xor(a3, 16); a3 += __shfl_xor(a3, 32);
  if (lane < 16) {
    if (bias) {
      float4 bv = ((const float4*)bias)[fj];
      a0 += bv.x; a1 += bv.y; a2 += bv.z; a3 += bv.w;
    }
    ((float4*)out)[(long)wid * 16 + fj] = make_float4(a0, a1, a2, a3);
  }
}

// ---------------- fallback kernels (R1 atomic path, f32) ----------------

__global__ __launch_bounds__(256) void gemm1_f32(
    const float* __restrict__ emb, const float* __restrict__ W1,
    float* __restrict__ x1, int N) {
  __shared__ float Ws[DIN * DH];
  __shared__ float rows[4][DIN];
  int tid = threadIdx.x;
  for (int i = tid; i < DIN * DH; i += 256) Ws[i] = W1[i];
  int r0 = blockIdx.x * 4;
  for (int i = tid; i < 4 * DIN; i += 256) {
    int rr = i >> 7, kk = i & 127;
    int r = r0 + rr;
    rows[rr][kk] = (r < N) ? emb[(long)r * DIN + kk] : 0.f;
  }
  __syncthreads();
  int rr = tid >> 6, j = tid & 63;
  int r = r0 + rr;
  float acc = 0.f;
#pragma unroll
  for (int k = 0; k < DIN; ++k) acc += rows[rr][k] * Ws[k * DH + j];
  if (r < N) x1[(long)r * DH + j] = acc;
}

__global__ __launch_bounds__(256) void gemm2_f32(
    const float* __restrict__ agg, const float* __restrict__ W2,
    const float* __restrict__ b1, float* __restrict__ x2, int N) {
  __shared__ float Ws[DH * DH];
  __shared__ float rows[4][DH];
  int tid = threadIdx.x;
  for (int i = tid; i < DH * DH; i += 256) Ws[i] = W2[i];
  int r0 = blockIdx.x * 4;
  {
    int rr = tid >> 6, kk = tid & 63;
    int r = r0 + rr;
    float v = (r < N) ? agg[(long)r * DH + kk] + b1[kk] : 0.f;
    rows[rr][kk] = v > 0.f ? v : 0.f;
  }
  __syncthreads();
  int rr = tid >> 6, j = tid & 63;
  float acc = 0.f;
#pragma unroll
  for (int k = 0; k < DH; ++k) acc += rows[rr][k] * Ws[k * DH + j];
  int r = r0 + rr;
  if (r < N) x2[(long)r * DH + j] = acc;
}

__global__ __launch_bounds__(256) void init_bias_kernel(
    float* __restrict__ out, const float* __restrict__ b2, int total) {
  int i = blockIdx.x * 256 + threadIdx.x;
  if (i < total) out[i] = b2[i & 63];
}

__global__ __launch_bounds__(256) void scatter_kernel(
    const int* __restrict__ srcs, const int* __restrict__ dsts,
    const float* __restrict__ w, const float* __restrict__ x,
    float* __restrict__ out, int E) {
  long t = (long)blockIdx.x * 256 + threadIdx.x;
  long e = t >> 6;
  if (e >= E) return;
  int j = (int)(t & 63);
  int s = srcs[e];
  int d = dsts[e];
  float val = w[e] * x[(long)s * DH + j];
  atomicAdd(&out[(long)d * DH + j], val);
}

// ---------------- host ----------------

static inline size_t align256(size_t x) { return (x + 255) & ~(size_t)255; }

extern "C" void kernel_launch(void* const* d_in, const int* in_sizes, int n_in,
                              void* d_out, int out_size, void* d_ws, size_t ws_size,
                              hipStream_t stream) {
  const int*   edge_index = (const int*)d_in[0];
  const float* edge_w     = (const float*)d_in[1];
  const float* emb        = (const float*)d_in[2];
  const float* W1         = (const float*)d_in[3];
  const float* b1         = (const float*)d_in[4];
  const float* W2         = (const float*)d_in[5];
  const float* b2         = (const float*)d_in[6];
  float* out = (float*)d_out;

  const int E = in_sizes[0] / 2;
  const int N = NNODES;
  const int* srcs = edge_index;
  const int* dsts = edge_index + E;

  const size_t xbytes_bf  = (size_t)N * DH * sizeof(__hip_bfloat16);  // 12.8 MB
  const size_t eswbytes   = (size_t)E * sizeof(int2);                 // 25.6 MB
  const size_t pairsbytes = (size_t)E * sizeof(int);                  // 12.8 MB
  const size_t offsbytes  = (size_t)(N + 1) * sizeof(int);

  const int aggBlocks = (N + 3) / 4;
  const int gemmBlocks = (N + 127) / 128;   // 128 rows per block (4 waves x 32 rows)

  size_t off = 0;
  char* base = (char*)d_ws;
  int2* esw   = (int2*)(base + off);
  off = align256(off + (eswbytes > xbytes_bf ? eswbytes : xbytes_bf));
  __hip_bfloat16* xbuf = (__hip_bfloat16*)esw;   // alias: esw dead after csr_build
  int*  pairs = (int*)(base + off);  off = align256(off + pairsbytes);
  int*  offs  = (int*)(base + off);  off = align256(off + offsbytes);
  int*  bcnt  = (int*)(base + off);  off = align256(off + (NBUCK + 1) * sizeof(int));
  int*  bOffs = (int*)(base + off);  off = align256(off + (NBUCK + 1) * sizeof(int));
  int*  bCur  = (int*)(base + off);  off = align256(off + NBUCK * sizeof(int));
  const size_t needed_full = off;

  if (ws_size >= needed_full) {
    // ---- bucketed CSR build (once, reused by both layers) ----
    hipMemsetAsync(bcnt, 0, NBUCK * sizeof(int), stream);
    bucket_hist<<<(E + 4095) / 4096, 256, 0, stream>>>(dsts, bcnt, E);
    bucket_scan<<<1, 256, 0, stream>>>(bcnt, bOffs, bCur, offs, N);
    bucket_fill<<<(E + 8191) / 8192, 512, 0, stream>>>(srcs, dsts, edge_w, bCur, esw, E);
    csr_build<<<NBUCK, 512, 0, stream>>>(esw, bOffs, offs, pairs, N);

    // ---- layer 1: x1 = bf16(emb@W1); agg1 = A@x1 (into d_out, f32) ----
    gemm1_mfma<<<gemmBlocks, 256, 0, stream>>>(emb, W1, xbuf, N);
    agg_quad<<<aggBlocks, 256, 0, stream>>>(pairs, offs, (const uint2*)xbuf, nullptr, out, N);

    // ---- layer 2: x2 = bf16(relu(agg1+b1)@W2); out = A@x2 + b2 ----
    gemm2_mfma<<<gemmBlocks, 256, 0, stream>>>(out, W2, b1, xbuf, N);
    agg_quad<<<aggBlocks, 256, 0, stream>>>(pairs, offs, (const uint2*)xbuf, b2, out, N);
    return;
  }

  // ---- R1 fallback: atomic scatter (needs only N*64 f32) ----
  const long scatterThreads = (long)E * 64;
  const int scatterBlocks = (int)((scatterThreads + 255) / 256);
  const int rowBlocks4 = (N + 3) / 4;
  float* xb1 = (float*)d_ws;

  gemm1_f32<<<rowBlocks4, 256, 0, stream>>>(emb, W1, xb1, N);
  hipMemsetAsync(d_out, 0, (size_t)N * DH * sizeof(float), stream);
  scatter_kernel<<<scatterBlocks, 256, 0, stream>>>(srcs, dsts, edge_w, xb1, out, E);

  gemm2_f32<<<rowBlocks4, 256, 0, stream>>>(out, W2, b1, xb1, N);
  init_bias_kernel<<<(N * DH + 255) / 256, 256, 0, stream>>>(out, b2, N * DH);
  scatter_kernel<<<scatterBlocks, 256, 0, stream>>>(srcs, dsts, edge_w, xb1, out, E);
}

// Round 2
// 225.728 us; speedup vs baseline: 1.3300x; 1.1560x over previous
//
#include <hip/hip_runtime.h>
#include <hip/hip_bf16.h>

#define NNODES 100000
#define DIN 128
#define DH 64
#define BSH 9
#define BNODES 512                             // 1 << BSH
#define NBUCK ((NNODES + BNODES - 1) >> BSH)   // 196
#define SRCMASK 0x1FFFF                        // N < 2^17

typedef short s16x8 __attribute__((ext_vector_type(8)));
typedef float f32x4 __attribute__((ext_vector_type(4)));

static __device__ __forceinline__ short f2bf(float f) {
  __hip_bfloat16 h = __float2bfloat16(f);   // RTNE
  return *reinterpret_cast<short*>(&h);
}
static __device__ __forceinline__ float bf2f(short s) {
  return __uint_as_float(((unsigned)(unsigned short)s) << 16);
}

// ---------------- dense transforms via MFMA (hi/lo bf16 split ~ 17-bit mantissa) ----------------
// mfma_f32_16x16x32_bf16 layouts (m89-verified):
//   A: row = lane&15, k = (lane>>4)*8 + i
//   B: col = lane&15, k = (lane>>4)*8 + i
//   D: col = lane&15, row = (lane>>4)*4 + reg
// Each wave: 32 output rows (2 row-tiles of 16) x 64 cols (4 col-tiles of 16).
// Block = 4 waves = 128 rows. W staged once per block into LDS in fragment order.

__global__ __launch_bounds__(256, 4) void gemm1_mfma(
    const float* __restrict__ emb, const float* __restrict__ W1,
    __hip_bfloat16* __restrict__ x1, int N) {
  __shared__ short Bhi[4 * 4 * 64 * 8];   // [kc][ct][lane][8] = 8192 bf16 = 16 KB
  __shared__ short Blo[4 * 4 * 64 * 8];   // 16 KB
  int tid = threadIdx.x;

  for (int idx = tid; idx < 8192; idx += 256) {
    int i = idx & 7, ln = (idx >> 3) & 63, ct = (idx >> 9) & 3, kc = idx >> 11;
    int k = kc * 32 + (ln >> 4) * 8 + i;
    int col = ct * 16 + (ln & 15);
    float w = W1[k * DH + col];
    short h = f2bf(w);
    Bhi[idx] = h;
    Blo[idx] = f2bf(w - bf2f(h));
  }
  __syncthreads();

  int lane = tid & 63, wv = tid >> 6;
  int r0 = (blockIdx.x * 8 + wv * 2) * 16;   // this wave: rows r0 .. r0+31
  if (r0 >= N) return;

  const int rA = lane & 15, g = lane >> 4;
  f32x4 acc[2][4] = {};

#pragma unroll
  for (int kc = 0; kc < 4; ++kc) {
    s16x8 ahi[2], alo[2];
#pragma unroll
    for (int rt = 0; rt < 2; ++rt) {
      int r = r0 + rt * 16 + rA;
      float av[8];
      if (r < N) {
        const float4* ap = (const float4*)(emb + (long)r * DIN + kc * 32 + g * 8);
        float4 v0 = ap[0], v1 = ap[1];
        av[0] = v0.x; av[1] = v0.y; av[2] = v0.z; av[3] = v0.w;
        av[4] = v1.x; av[5] = v1.y; av[6] = v1.z; av[7] = v1.w;
      } else {
#pragma unroll
        for (int i = 0; i < 8; ++i) av[i] = 0.f;
      }
#pragma unroll
      for (int i = 0; i < 8; ++i) {
        short h = f2bf(av[i]);
        ahi[rt][i] = h;
        alo[rt][i] = f2bf(av[i] - bf2f(h));
      }
    }
#pragma unroll
    for (int ct = 0; ct < 4; ++ct) {
      int fo = ((kc * 4 + ct) * 64 + lane) * 8;
      s16x8 bh = *(const s16x8*)&Bhi[fo];
      s16x8 bl = *(const s16x8*)&Blo[fo];
#pragma unroll
      for (int rt = 0; rt < 2; ++rt) {
        acc[rt][ct] = __builtin_amdgcn_mfma_f32_16x16x32_bf16(ahi[rt], bh, acc[rt][ct], 0, 0, 0);
        acc[rt][ct] = __builtin_amdgcn_mfma_f32_16x16x32_bf16(alo[rt], bh, acc[rt][ct], 0, 0, 0);
        acc[rt][ct] = __builtin_amdgcn_mfma_f32_16x16x32_bf16(ahi[rt], bl, acc[rt][ct], 0, 0, 0);
      }
    }
  }

#pragma unroll
  for (int rt = 0; rt < 2; ++rt) {
#pragma unroll
    for (int j = 0; j < 4; ++j) {
      int row = r0 + rt * 16 + g * 4 + j;
      if (row < N) {
#pragma unroll
        for (int ct = 0; ct < 4; ++ct)
          x1[(long)row * DH + ct * 16 + rA] = __float2bfloat16(acc[rt][ct][j]);
      }
    }
  }
}

__global__ __launch_bounds__(256, 4) void gemm2_mfma(
    const float* __restrict__ agg, const float* __restrict__ W2,
    const float* __restrict__ b1, __hip_bfloat16* __restrict__ x2, int N) {
  __shared__ short Bhi[2 * 4 * 64 * 8];   // 4096 bf16 = 8 KB
  __shared__ short Blo[2 * 4 * 64 * 8];   // 8 KB
  int tid = threadIdx.x;

  for (int idx = tid; idx < 4096; idx += 256) {
    int i = idx & 7, ln = (idx >> 3) & 63, ct = (idx >> 9) & 3, kc = (idx >> 11) & 1;
    int k = kc * 32 + (ln >> 4) * 8 + i;
    int col = ct * 16 + (ln & 15);
    float w = W2[k * DH + col];
    short h = f2bf(w);
    Bhi[idx] = h;
    Blo[idx] = f2bf(w - bf2f(h));
  }
  __syncthreads();

  int lane = tid & 63, wv = tid >> 6;
  int r0 = (blockIdx.x * 8 + wv * 2) * 16;
  if (r0 >= N) return;

  const int rA = lane & 15, g = lane >> 4;
  f32x4 acc[2][4] = {};

#pragma unroll
  for (int kc = 0; kc < 2; ++kc) {
    const float4* bp = (const float4*)(b1 + kc * 32 + g * 8);
    float4 b0 = bp[0], b4 = bp[1];
    float bv[8] = {b0.x, b0.y, b0.z, b0.w, b4.x, b4.y, b4.z, b4.w};
    s16x8 ahi[2], alo[2];
#pragma unroll
    for (int rt = 0; rt < 2; ++rt) {
      int r = r0 + rt * 16 + rA;
      float av[8];
      if (r < N) {
        const float4* ap = (const float4*)(agg + (long)r * DH + kc * 32 + g * 8);
        float4 v0 = ap[0], v1 = ap[1];
        av[0] = v0.x; av[1] = v0.y; av[2] = v0.z; av[3] = v0.w;
        av[4] = v1.x; av[5] = v1.y; av[6] = v1.z; av[7] = v1.w;
      } else {
#pragma unroll
        for (int i = 0; i < 8; ++i) av[i] = -1e30f;  // relu() -> 0 anyway
      }
#pragma unroll
      for (int i = 0; i < 8; ++i) {
        float a = fmaxf(av[i] + bv[i], 0.f);
        short h = f2bf(a);
        ahi[rt][i] = h;
        alo[rt][i] = f2bf(a - bf2f(h));
      }
    }
#pragma unroll
    for (int ct = 0; ct < 4; ++ct) {
      int fo = ((kc * 4 + ct) * 64 + lane) * 8;
      s16x8 bh = *(const s16x8*)&Bhi[fo];
      s16x8 bl = *(const s16x8*)&Blo[fo];
#pragma unroll
      for (int rt = 0; rt < 2; ++rt) {
        acc[rt][ct] = __builtin_amdgcn_mfma_f32_16x16x32_bf16(ahi[rt], bh, acc[rt][ct], 0, 0, 0);
        acc[rt][ct] = __builtin_amdgcn_mfma_f32_16x16x32_bf16(alo[rt], bh, acc[rt][ct], 0, 0, 0);
        acc[rt][ct] = __builtin_amdgcn_mfma_f32_16x16x32_bf16(ahi[rt], bl, acc[rt][ct], 0, 0, 0);
      }
    }
  }

#pragma unroll
  for (int rt = 0; rt < 2; ++rt) {
#pragma unroll
    for (int j = 0; j < 4; ++j) {
      int row = r0 + rt * 16 + g * 4 + j;
      if (row < N) {
#pragma unroll
        for (int ct = 0; ct < 4; ++ct)
          x2[(long)row * DH + ct * 16 + rA] = __float2bfloat16(acc[rt][ct][j]);
      }
    }
  }
}

// ---------------- bucketed CSR build ----------------

__global__ __launch_bounds__(256) void bucket_hist(
    const int* __restrict__ dsts, int* __restrict__ bcnt, int E) {
  __shared__ int c[NBUCK];
  for (int i = threadIdx.x; i < NBUCK; i += 256) c[i] = 0;
  __syncthreads();
  int e0 = blockIdx.x * 4096;
  int e1 = min(E, e0 + 4096);
  for (int e = e0 + threadIdx.x; e < e1; e += 256)
    atomicAdd(&c[dsts[e] >> BSH], 1);
  __syncthreads();
  for (int i = threadIdx.x; i < NBUCK; i += 256)
    if (c[i]) atomicAdd(&bcnt[i], c[i]);
}

__global__ __launch_bounds__(256) void bucket_scan(
    const int* __restrict__ bcnt, int* __restrict__ bOffs,
    int* __restrict__ bCur, int* __restrict__ offs, int N) {
  int t = threadIdx.x;
  __shared__ int s[256];
  int v = (t < NBUCK) ? bcnt[t] : 0;
  s[t] = v;
  __syncthreads();
  for (int d = 1; d < 256; d <<= 1) {
    int u = (t >= d) ? s[t - d] : 0;
    __syncthreads();
    s[t] += u;
    __syncthreads();
  }
  if (t < NBUCK) { bOffs[t] = s[t] - v; bCur[t] = s[t] - v; }
  if (t == NBUCK - 1) { bOffs[NBUCK] = s[t]; offs[N] = s[t]; }
}

__global__ __launch_bounds__(512) void bucket_fill(
    const int* __restrict__ srcs, const int* __restrict__ dsts,
    const float* __restrict__ w, int* __restrict__ bCur,
    int2* __restrict__ esw, int E) {
  __shared__ int cnt[NBUCK];
  __shared__ int base[NBUCK];
  int tid = threadIdx.x;
  for (int i = tid; i < NBUCK; i += 512) cnt[i] = 0;
  __syncthreads();
  int e0 = blockIdx.x * 8192;
  int pk[16]; int bs[16]; float ww[16];
#pragma unroll
  for (int i = 0; i < 16; ++i) {
    int e = e0 + tid + i * 512;
    if (e < E) {
      int s = srcs[e], d = dsts[e];
      pk[i] = s | ((d & (BNODES - 1)) << 17);
      bs[i] = d >> BSH;
      ww[i] = w[e];
    } else { bs[i] = -1; pk[i] = 0; ww[i] = 0.f; }
  }
#pragma unroll
  for (int i = 0; i < 16; ++i)
    if (bs[i] >= 0) atomicAdd(&cnt[bs[i]], 1);
  __syncthreads();
  for (int b = tid; b < NBUCK; b += 512)
    base[b] = cnt[b] ? atomicAdd(&bCur[b], cnt[b]) : 0;
  __syncthreads();
  for (int i = tid; i < NBUCK; i += 512) cnt[i] = 0;
  __syncthreads();
#pragma unroll
  for (int i = 0; i < 16; ++i) {
    if (bs[i] >= 0) {
      int p = base[bs[i]] + atomicAdd(&cnt[bs[i]], 1);
      esw[p] = make_int2(pk[i], __float_as_int(ww[i]));
    }
  }
}

// one block per bucket: local hist+scan+scatter; writes PACKED 4B pairs:
// src(17 bits) | round(w*2^15)(15 bits) << 17   (w in [0,1))
__global__ __launch_bounds__(512) void csr_build(
    const int2* __restrict__ esw, const int* __restrict__ bOffs,
    int* __restrict__ offs, int* __restrict__ pairs, int N) {
  int b = blockIdx.x;
  int nb0 = b << BSH;
  int st = bOffs[b], en = bOffs[b + 1];
  __shared__ int deg[BNODES];
  __shared__ int cur[BNODES];
  int tid = threadIdx.x;
  deg[tid] = 0;
  __syncthreads();
  for (int k = st + tid; k < en; k += 512)
    atomicAdd(&deg[(esw[k].x >> 17) & (BNODES - 1)], 1);
  __syncthreads();
  int v = deg[tid];
  cur[tid] = v;
  __syncthreads();
  for (int d = 1; d < 512; d <<= 1) {
    int u = (tid >= d) ? cur[tid - d] : 0;
    __syncthreads();
    cur[tid] += u;
    __syncthreads();
  }
  int c = st + cur[tid] - v;
  cur[tid] = c;
  int n = nb0 + tid;
  if (n < N) offs[n] = c;
  __syncthreads();
  for (int k = st + tid; k < en; k += 512) {
    int2 e = esw[k];
    int p = atomicAdd(&cur[(e.x >> 17) & (BNODES - 1)], 1);
    float wv = __int_as_float(e.y);
    int wq = (int)(wv * 32768.f + 0.5f);
    if (wq > 32767) wq = 32767;
    pairs[p] = (e.x & SRCMASK) | (wq << 17);
  }
}

// ---------------- CSR aggregation: deep-MLP gather ----------------
// lane = h*16 + fj : h = edge-of-quad (0..3), fj = feature-quad (0..15).
// Per 64-edge block: ONE coalesced lane-parallel pairs load (padded with 0 =>
// w=0, harmless), values distributed via __shfl (no global latency in chain).
// First 32 edges (8 gather instrs) issue unconditionally back-to-back for MLP;
// edges 32..63 in 16-edge steps behind a wave-uniform break.
#define ACC4(P, XV)                                          \
  do {                                                       \
    float wv_ = (float)((P) >> 17) * (1.f / 32768.f);        \
    a0 += wv_ * __uint_as_float((XV).x << 16);               \
    a1 += wv_ * __uint_as_float((XV).x & 0xFFFF0000u);       \
    a2 += wv_ * __uint_as_float((XV).y << 16);               \
    a3 += wv_ * __uint_as_float((XV).y & 0xFFFF0000u);       \
  } while (0)

__global__ __launch_bounds__(256) void agg_quad(
    const int* __restrict__ pairs, const int* __restrict__ offs,
    const uint2* __restrict__ x,   // 4×bf16 per element, 16 per node
    const float* __restrict__ bias, float* __restrict__ out, int N) {
  int wid = (int)(((long)blockIdx.x * 256 + threadIdx.x) >> 6);
  int lane = threadIdx.x & 63;
  if (wid >= N) return;
  int h = lane >> 4;        // edge within quad
  int fj = lane & 15;       // feature-quad index
  int st = offs[wid], en = offs[wid + 1];
  float a0 = 0.f, a1 = 0.f, a2 = 0.f, a3 = 0.f;

  for (int base = st; base < en; base += 64) {
    int pl = (base + lane < en) ? pairs[base + lane] : 0;  // coalesced, padded
    int m = en - base;

    // edges base+0 .. base+31: 8 independent gathers in flight
    unsigned pg[8];
#pragma unroll
    for (int g = 0; g < 8; ++g) pg[g] = (unsigned)__shfl(pl, g * 4 + h);
    uint2 xg[8];
#pragma unroll
    for (int g = 0; g < 8; ++g) xg[g] = x[(pg[g] & SRCMASK) * 16 + fj];
#pragma unroll
    for (int g = 0; g < 8; ++g) ACC4(pg[g], xg[g]);

    // edges base+32 .. base+63: 16-edge steps, wave-uniform early exit
#pragma unroll
    for (int q = 32; q < 64; q += 16) {
      if (q >= m) break;
      unsigned p0 = (unsigned)__shfl(pl, q + h);
      unsigned p1 = (unsigned)__shfl(pl, q + 4 + h);
      unsigned p2 = (unsigned)__shfl(pl, q + 8 + h);
      unsigned p3 = (unsigned)__shfl(pl, q + 12 + h);
      uint2 y0 = x[(p0 & SRCMASK) * 16 + fj];
      uint2 y1 = x[(p1 & SRCMASK) * 16 + fj];
      uint2 y2 = x[(p2 & SRCMASK) * 16 + fj];
      uint2 y3 = x[(p3 & SRCMASK) * 16 + fj];
      ACC4(p0, y0); ACC4(p1, y1); ACC4(p2, y2); ACC4(p3, y3);
    }
  }

  // sum over the 4 edge-groups (h); lanes with equal fj hold same features
  a0 += __shfl_xor(a0, 16); a0 += __shfl_xor(a0, 32);
  a1 += __shfl_xor(a1, 16); a1 += __shfl_xor(a1, 32);
  a2 += __shfl_xor(a2, 16); a2 += __shfl_xor(a2, 32);
  a3 += __shfl_xor(a3, 16); a3 += __shfl_xor(a3, 32);
  if (lane < 16) {
    if (bias) {
      float4 bv = ((const float4*)bias)[fj];
      a0 += bv.x; a1 += bv.y; a2 += bv.z; a3 += bv.w;
    }
    ((float4*)out)[(long)wid * 16 + fj] = make_float4(a0, a1, a2, a3);
  }
}

// ---------------- fallback kernels (R1 atomic path, f32) ----------------

__global__ __launch_bounds__(256) void gemm1_f32(
    const float* __restrict__ emb, const float* __restrict__ W1,
    float* __restrict__ x1, int N) {
  __shared__ float Ws[DIN * DH];
  __shared__ float rows[4][DIN];
  int tid = threadIdx.x;
  for (int i = tid; i < DIN * DH; i += 256) Ws[i] = W1[i];
  int r0 = blockIdx.x * 4;
  for (int i = tid; i < 4 * DIN; i += 256) {
    int rr = i >> 7, kk = i & 127;
    int r = r0 + rr;
    rows[rr][kk] = (r < N) ? emb[(long)r * DIN + kk] : 0.f;
  }
  __syncthreads();
  int rr = tid >> 6, j = tid & 63;
  int r = r0 + rr;
  float acc = 0.f;
#pragma unroll
  for (int k = 0; k < DIN; ++k) acc += rows[rr][k] * Ws[k * DH + j];
  if (r < N) x1[(long)r * DH + j] = acc;
}

__global__ __launch_bounds__(256) void gemm2_f32(
    const float* __restrict__ agg, const float* __restrict__ W2,
    const float* __restrict__ b1, float* __restrict__ x2, int N) {
  __shared__ float Ws[DH * DH];
  __shared__ float rows[4][DH];
  int tid = threadIdx.x;
  for (int i = tid; i < DH * DH; i += 256) Ws[i] = W2[i];
  int r0 = blockIdx.x * 4;
  {
    int rr = tid >> 6, kk = tid & 63;
    int r = r0 + rr;
    float v = (r < N) ? agg[(long)r * DH + kk] + b1[kk] : 0.f;
    rows[rr][kk] = v > 0.f ? v : 0.f;
  }
  __syncthreads();
  int rr = tid >> 6, j = tid & 63;
  float acc = 0.f;
#pragma unroll
  for (int k = 0; k < DH; ++k) acc += rows[rr][k] * Ws[k * DH + j];
  int r = r0 + rr;
  if (r < N) x2[(long)r * DH + j] = acc;
}

__global__ __launch_bounds__(256) void init_bias_kernel(
    float* __restrict__ out, const float* __restrict__ b2, int total) {
  int i = blockIdx.x * 256 + threadIdx.x;
  if (i < total) out[i] = b2[i & 63];
}

__global__ __launch_bounds__(256) void scatter_kernel(
    const int* __restrict__ srcs, const int* __restrict__ dsts,
    const float* __restrict__ w, const float* __restrict__ x,
    float* __restrict__ out, int E) {
  long t = (long)blockIdx.x * 256 + threadIdx.x;
  long e = t >> 6;
  if (e >= E) return;
  int j = (int)(t & 63);
  int s = srcs[e];
  int d = dsts[e];
  float val = w[e] * x[(long)s * DH + j];
  atomicAdd(&out[(long)d * DH + j], val);
}

// ---------------- host ----------------

static inline size_t align256(size_t x) { return (x + 255) & ~(size_t)255; }

extern "C" void kernel_launch(void* const* d_in, const int* in_sizes, int n_in,
                              void* d_out, int out_size, void* d_ws, size_t ws_size,
                              hipStream_t stream) {
  const int*   edge_index = (const int*)d_in[0];
  const float* edge_w     = (const float*)d_in[1];
  const float* emb        = (const float*)d_in[2];
  const float* W1         = (const float*)d_in[3];
  const float* b1         = (const float*)d_in[4];
  const float* W2         = (const float*)d_in[5];
  const float* b2         = (const float*)d_in[6];
  float* out = (float*)d_out;

  const int E = in_sizes[0] / 2;
  const int N = NNODES;
  const int* srcs = edge_index;
  const int* dsts = edge_index + E;

  const size_t xbytes_bf  = (size_t)N * DH * sizeof(__hip_bfloat16);  // 12.8 MB
  const size_t eswbytes   = (size_t)E * sizeof(int2);                 // 25.6 MB
  const size_t pairsbytes = (size_t)E * sizeof(int);                  // 12.8 MB
  const size_t offsbytes  = (size_t)(N + 1) * sizeof(int);

  const int aggBlocks = (N + 3) / 4;
  const int gemmBlocks = (N + 127) / 128;   // 128 rows per block (4 waves x 32 rows)

  size_t off = 0;
  char* base = (char*)d_ws;
  int2* esw   = (int2*)(base + off);
  off = align256(off + (eswbytes > xbytes_bf ? eswbytes : xbytes_bf));
  __hip_bfloat16* xbuf = (__hip_bfloat16*)esw;   // alias: esw dead after csr_build
  int*  pairs = (int*)(base + off);  off = align256(off + pairsbytes);
  int*  offs  = (int*)(base + off);  off = align256(off + offsbytes);
  int*  bcnt  = (int*)(base + off);  off = align256(off + (NBUCK + 1) * sizeof(int));
  int*  bOffs = (int*)(base + off);  off = align256(off + (NBUCK + 1) * sizeof(int));
  int*  bCur  = (int*)(base + off);  off = align256(off + NBUCK * sizeof(int));
  const size_t needed_full = off;

  if (ws_size >= needed_full) {
    // ---- bucketed CSR build (once, reused by both layers) ----
    hipMemsetAsync(bcnt, 0, NBUCK * sizeof(int), stream);
    bucket_hist<<<(E + 4095) / 4096, 256, 0, stream>>>(dsts, bcnt, E);
    bucket_scan<<<1, 256, 0, stream>>>(bcnt, bOffs, bCur, offs, N);
    bucket_fill<<<(E + 8191) / 8192, 512, 0, stream>>>(srcs, dsts, edge_w, bCur, esw, E);
    csr_build<<<NBUCK, 512, 0, stream>>>(esw, bOffs, offs, pairs, N);

    // ---- layer 1: x1 = bf16(emb@W1); agg1 = A@x1 (into d_out, f32) ----
    gemm1_mfma<<<gemmBlocks, 256, 0, stream>>>(emb, W1, xbuf, N);
    agg_quad<<<aggBlocks, 256, 0, stream>>>(pairs, offs, (const uint2*)xbuf, nullptr, out, N);

    // ---- layer 2: x2 = bf16(relu(agg1+b1)@W2); out = A@x2 + b2 ----
    gemm2_mfma<<<gemmBlocks, 256, 0, stream>>>(out, W2, b1, xbuf, N);
    agg_quad<<<aggBlocks, 256, 0, stream>>>(pairs, offs, (const uint2*)xbuf, b2, out, N);
    return;
  }

  // ---- R1 fallback: atomic scatter (needs only N*64 f32) ----
  const long scatterThreads = (long)E * 64;
  const int scatterBlocks = (int)((scatterThreads + 255) / 256);
  const int rowBlocks4 = (N + 3) / 4;
  float* xb1 = (float*)d_ws;

  gemm1_f32<<<rowBlocks4, 256, 0, stream>>>(emb, W1, xb1, N);
  hipMemsetAsync(d_out, 0, (size_t)N * DH * sizeof(float), stream);
  scatter_kernel<<<scatterBlocks, 256, 0, stream>>>(srcs, dsts, edge_w, xb1, out, E);

  gemm2_f32<<<rowBlocks4, 256, 0, stream>>>(out, W2, b1, xb1, N);
  init_bias_kernel<<<(N * DH + 255) / 256, 256, 0, stream>>>(out, b2, N * DH);
  scatter_kernel<<<scatterBlocks, 256, 0, stream>>>(srcs, dsts, edge_w, xb1, out, E);
}